// Round 1
// baseline (331.952 us; speedup 1.0000x reference)
//
#include <hip/hip_runtime.h>
#include <math.h>

#define NB 2
#define NS 2048
#define NHID 1024
#define NHEAD 16
#define DHEAD 64

typedef _Float16 half_t;
typedef _Float16 hx4 __attribute__((ext_vector_type(4)));
typedef _Float16 hx8 __attribute__((ext_vector_type(8)));
typedef float fx4 __attribute__((ext_vector_type(4)));

typedef const __attribute__((address_space(1))) void* gvp;
typedef __attribute__((address_space(3))) void* svp;

static __device__ __forceinline__ void gload16(const void* g, void* s) {
  __builtin_amdgcn_global_load_lds((gvp)g, (svp)s, 16, 0, 0);
}

static __device__ __forceinline__ float gelu_exact(float x) {
  return 0.5f * x * (1.0f + erff(x * 0.70710678118654752f));
}

// ---------------- pack hidden_states f32 -> f16 ----------------
__launch_bounds__(256)
__global__ void packx(const float* __restrict__ x, half_t* __restrict__ xb) {
  const int i = blockIdx.x * 256 + threadIdx.x;  // 1,048,576 threads, 4 elems each
  const fx4 v = ((const fx4*)x)[i];
  hx4 o;
#pragma unroll
  for (int j = 0; j < 4; ++j) o[j] = (half_t)v[j];
  ((hx4*)xb)[i] = o;
}

// ---------------- transpose + pack 4 weight matrices (K,N)->(N,K) f16 ----------------
__launch_bounds__(256)
__global__ void packw(const float* __restrict__ w0, const float* __restrict__ w1,
                      const float* __restrict__ w2, const float* __restrict__ w3,
                      half_t* __restrict__ o0, half_t* __restrict__ o1,
                      half_t* __restrict__ o2, half_t* __restrict__ o3) {
  __shared__ float tile[32][33];
  const int z = blockIdx.z;
  const float* w = (z == 0) ? w0 : (z == 1) ? w1 : (z == 2) ? w2 : w3;
  half_t* o = (z == 0) ? o0 : (z == 1) ? o1 : (z == 2) ? o2 : o3;
  const int n0 = blockIdx.x * 32, k0 = blockIdx.y * 32;
  const int tx = threadIdx.x, ty = threadIdx.y;  // (32,8)
#pragma unroll
  for (int i = 0; i < 4; ++i)
    tile[ty + i * 8][tx] = w[(size_t)(k0 + ty + i * 8) * NHID + n0 + tx];
  __syncthreads();
#pragma unroll
  for (int i = 0; i < 4; ++i)
    o[(size_t)(n0 + ty + i * 8) * NHID + k0 + tx] = (half_t)tile[tx][ty + i * 8];
}

// ---------------- reach/attract scalar MLPs: (B,S) -> (B,NH,S) ----------------
__launch_bounds__(256)
__global__ void mlp16(const float* __restrict__ imp,
                      const float* __restrict__ rw1, const float* __restrict__ rb1,
                      const float* __restrict__ rw2, const float* __restrict__ rb2,
                      const float* __restrict__ aw1, const float* __restrict__ ab1,
                      const float* __restrict__ aw2, const float* __restrict__ ab2,
                      float* __restrict__ reach, float* __restrict__ attract) {
  const int i = blockIdx.x * 256 + threadIdx.x;  // 0..4095 == b*NS+s
  const float v = imp[i];
  const int b = i >> 11, s = i & (NS - 1);
  float ra[16] = {}, aa[16] = {};
  for (int m = 0; m < 32; ++m) {
    const float hr = gelu_exact(v * rw1[m] + rb1[m]);
    const float ha = gelu_exact(v * aw1[m] + ab1[m]);
#pragma unroll
    for (int h = 0; h < 16; ++h) {
      ra[h] += hr * rw2[m * 16 + h];
      aa[h] += ha * aw2[m * 16 + h];
    }
  }
#pragma unroll
  for (int h = 0; h < 16; ++h) {
    reach[(size_t)(b * NHEAD + h) * NS + s] = ra[h] + rb2[h];
    attract[(size_t)(b * NHEAD + h) * NS + s] = aa[h] + ab2[h];
  }
}

// ---------------- fused QKV GEMM: 128x128 tile, BK=32, 4 waves, m97 structure ----------------
// A: (4096,1024) f16   Bt: (N=1024,K=1024) f16 (pre-transposed weight)
// z=0: Q -> (b,s,h,d) scaled by 1/8 ; z=1: K -> (b,s,h,d) ; z=2: V -> (b,h,d,s) transposed
__launch_bounds__(256, 2)
__global__ void gemm_qkv(const half_t* __restrict__ A,
                         const half_t* __restrict__ Wq, const half_t* __restrict__ Wk,
                         const half_t* __restrict__ Wv,
                         const float* __restrict__ bq, const float* __restrict__ bk,
                         const float* __restrict__ bv,
                         half_t* __restrict__ Qo, half_t* __restrict__ Ko,
                         half_t* __restrict__ Vo) {
  __shared__ __align__(16) half_t As[128 * 32];
  __shared__ __align__(16) half_t Bs[128 * 32];
  const int z = blockIdx.z;
  const half_t* Bt = (z == 0) ? Wq : (z == 1) ? Wk : Wv;
  const float* bias = (z == 0) ? bq : (z == 1) ? bk : bv;

  const int t = threadIdx.x;
  const int l = t & 63, w = t >> 6;
  const int lo = l & 15, g = l >> 4;
  const int m0 = blockIdx.x * 128, n0 = blockIdx.y * 128;
  const int wm = (w >> 1) * 64, wn = (w & 1) * 64;
  fx4 acc[4][4] = {};

  for (int k0 = 0; k0 < NHID; k0 += 32) {
#pragma unroll
    for (int i = 0; i < 2; ++i) {
      const int c = i * 256 + t;
      const int row = c >> 2, kc = (c & 3) * 8;
      gload16(A + (size_t)(m0 + row) * NHID + k0 + kc, As + c * 8);
      gload16(Bt + (size_t)(n0 + row) * NHID + k0 + kc, Bs + c * 8);
    }
    __syncthreads();
    hx8 af[4], bfv[4];
#pragma unroll
    for (int i = 0; i < 4; ++i) {
      af[i] = *(const hx8*)(As + (wm + i * 16 + lo) * 32 + g * 8);
      bfv[i] = *(const hx8*)(Bs + (wn + i * 16 + lo) * 32 + g * 8);
    }
#pragma unroll
    for (int mi = 0; mi < 4; ++mi)
#pragma unroll
      for (int ni = 0; ni < 4; ++ni)
        acc[mi][ni] = __builtin_amdgcn_mfma_f32_16x16x32_f16(af[mi], bfv[ni], acc[mi][ni], 0, 0, 0);
    __syncthreads();
  }

#pragma unroll
  for (int mi = 0; mi < 4; ++mi) {
    const int r0 = m0 + wm + mi * 16 + g * 4;
#pragma unroll
    for (int ni = 0; ni < 4; ++ni) {
      const int col = n0 + wn + ni * 16 + lo;
      const float bs = bias[col];
      if (z == 2) {
        const int b = r0 >> 11, s = r0 & (NS - 1);
        const int h = col >> 6, d = col & 63;
        hx4 v;
#pragma unroll
        for (int j = 0; j < 4; ++j) v[j] = (half_t)(acc[mi][ni][j] + bs);
        *(hx4*)(Vo + ((size_t)((b * NHEAD + h) * DHEAD + d)) * NS + s) = v;
      } else if (z == 0) {
#pragma unroll
        for (int j = 0; j < 4; ++j)
          Qo[(size_t)(r0 + j) * NHID + col] = (half_t)((acc[mi][ni][j] + bs) * 0.125f);
      } else {
#pragma unroll
        for (int j = 0; j < 4; ++j)
          Ko[(size_t)(r0 + j) * NHID + col] = (half_t)(acc[mi][ni][j] + bs);
      }
    }
  }
}

// ---------------- output projection GEMM + bias + residual -> f32 ----------------
__launch_bounds__(256, 2)
__global__ void gemm_o(const half_t* __restrict__ A, const half_t* __restrict__ Bt,
                       const float* __restrict__ bias, const float* __restrict__ resid,
                       float* __restrict__ outf) {
  __shared__ __align__(16) half_t As[128 * 32];
  __shared__ __align__(16) half_t Bs[128 * 32];
  const int t = threadIdx.x;
  const int l = t & 63, w = t >> 6;
  const int lo = l & 15, g = l >> 4;
  const int m0 = blockIdx.x * 128, n0 = blockIdx.y * 128;
  const int wm = (w >> 1) * 64, wn = (w & 1) * 64;
  fx4 acc[4][4] = {};

  for (int k0 = 0; k0 < NHID; k0 += 32) {
#pragma unroll
    for (int i = 0; i < 2; ++i) {
      const int c = i * 256 + t;
      const int row = c >> 2, kc = (c & 3) * 8;
      gload16(A + (size_t)(m0 + row) * NHID + k0 + kc, As + c * 8);
      gload16(Bt + (size_t)(n0 + row) * NHID + k0 + kc, Bs + c * 8);
    }
    __syncthreads();
    hx8 af[4], bfv[4];
#pragma unroll
    for (int i = 0; i < 4; ++i) {
      af[i] = *(const hx8*)(As + (wm + i * 16 + lo) * 32 + g * 8);
      bfv[i] = *(const hx8*)(Bs + (wn + i * 16 + lo) * 32 + g * 8);
    }
#pragma unroll
    for (int mi = 0; mi < 4; ++mi)
#pragma unroll
      for (int ni = 0; ni < 4; ++ni)
        acc[mi][ni] = __builtin_amdgcn_mfma_f32_16x16x32_f16(af[mi], bfv[ni], acc[mi][ni], 0, 0, 0);
    __syncthreads();
  }

#pragma unroll
  for (int mi = 0; mi < 4; ++mi) {
    const int r0 = m0 + wm + mi * 16 + g * 4;
#pragma unroll
    for (int ni = 0; ni < 4; ++ni) {
      const int col = n0 + wn + ni * 16 + lo;
      const float bs = bias[col];
#pragma unroll
      for (int j = 0; j < 4; ++j) {
        const size_t idx = (size_t)(r0 + j) * NHID + col;
        outf[idx] = acc[mi][ni][j] + bs + resid[idx];
      }
    }
  }
}

// ---------------- fused flash attention with importance mask bias ----------------
// Q (b,s,h,d) pre-scaled by 1/8; K (b,s,h,d); Vt (b,h,d,s). 4 waves; wave w owns 16 q's.
// Swapped QK^T: S^T = mfma(Kfrag, Qfrag); each lane holds one q column -> in-lane softmax.
__launch_bounds__(256, 2)
__global__ void attn64(const half_t* __restrict__ Qb, const half_t* __restrict__ Kb,
                       const half_t* __restrict__ Vtb,
                       const float* __restrict__ reach, const float* __restrict__ attract,
                       const float* __restrict__ ltemp,
                       half_t* __restrict__ O) {
  __shared__ __align__(16) half_t Ks[64 * 64];      // swizzled (chunk ^= row&7)
  __shared__ __align__(16) half_t Vs[64 * 64];      // swizzled, holds V^T tile [d][kv]
  __shared__ __align__(16) half_t Ps[4][16 * 80];   // per-wave P [q][kv], stride 80
  __shared__ float attS[64];

  const int t = threadIdx.x;
  const int l = t & 63, w = t >> 6;
  const int lo = l & 15, g = l >> 4;
  const int bh = blockIdx.y;
  const int b = bh >> 4, h = bh & 15;
  const int q0 = blockIdx.x * 64;
  const int q = q0 + w * 16 + lo;

  const float invtemp = 1.0f / (__expf(ltemp[h]) + 1.0f);
  const float ndc = invtemp * (1.0f / (float)NS);
  const float rq = reach[(size_t)bh * NS + q];

  hx8 qf[2];
  {
    const half_t* qp = Qb + (size_t)(b * NS + q) * NHID + h * DHEAD + g * 8;
    qf[0] = *(const hx8*)(qp);
    qf[1] = *(const hx8*)(qp + 32);
  }

  fx4 o[4] = {};
  float m_run = -INFINITY, s_run = 0.0f;

  const half_t* Kbase = Kb + (size_t)b * (NS * NHID) + h * DHEAD;
  const half_t* Vbase = Vtb + (size_t)bh * (DHEAD * NS);
  const float* abase = attract + (size_t)bh * NS;

  for (int kv0 = 0; kv0 < NS; kv0 += 64) {
#pragma unroll
    for (int i = 0; i < 2; ++i) {
      const int c = i * 256 + t;
      const int row = c >> 3;
      const int ca = (c & 7) ^ (row & 7);  // pre-swizzle the global source chunk
      gload16(Kbase + (size_t)(kv0 + row) * NHID + ca * 8, Ks + c * 8);
      gload16(Vbase + (size_t)row * NS + kv0 + ca * 8, Vs + c * 8);
    }
    if (t < 64) attS[t] = abase[kv0 + t];
    __syncthreads();

    // QK^T: S^T tile (64 kv x 16 q) per wave
    fx4 sa[4] = {};
#pragma unroll
    for (int mf = 0; mf < 4; ++mf) {
      const int row = mf * 16 + lo;
#pragma unroll
      for (int ks = 0; ks < 2; ++ks) {
        const hx8 kf = *(const hx8*)(Ks + row * 64 + (((ks * 4 + g) ^ (row & 7)) * 8));
        sa[mf] = __builtin_amdgcn_mfma_f32_16x16x32_f16(kf, qf[ks], sa[mf], 0, 0, 0);
      }
    }

    // online softmax; max tracked on raw logits, bias applied multiplicatively:
    // softmax(l + log(sig+eps)) == normalize(exp(l-m) * (sig+eps))
    float tmax = -INFINITY;
#pragma unroll
    for (int mf = 0; mf < 4; ++mf)
#pragma unroll
      for (int j = 0; j < 4; ++j) tmax = fmaxf(tmax, sa[mf][j]);
    tmax = fmaxf(tmax, __shfl_xor(tmax, 16));
    tmax = fmaxf(tmax, __shfl_xor(tmax, 32));
    const float m_new = fmaxf(m_run, tmax);
    const float alpha = __expf(m_run - m_new);

    float psum = 0.0f;
    hx4 pb[4];
#pragma unroll
    for (int mf = 0; mf < 4; ++mf) {
#pragma unroll
      for (int j = 0; j < 4; ++j) {
        const int kvl = mf * 16 + g * 4 + j;
        const float x = rq + attS[kvl] - fabsf((float)(q - (kv0 + kvl))) * ndc;
        const float e = __expf(sa[mf][j] - m_new);
        const float sg = 1.0f / (1.0f + __expf(-x));
        const float p = e * (sg + 1e-8f);
        psum += p;
        pb[mf][j] = (half_t)p;
      }
    }
    psum += __shfl_xor(psum, 16);
    psum += __shfl_xor(psum, 32);
    s_run = s_run * alpha + psum;
    m_run = m_new;
#pragma unroll
    for (int df = 0; df < 4; ++df) {
#pragma unroll
      for (int j = 0; j < 4; ++j) o[df][j] *= alpha;
    }
#pragma unroll
    for (int mf = 0; mf < 4; ++mf)
      *(hx4*)(&Ps[w][lo * 80 + mf * 16 + g * 4]) = pb[mf];

    // PV: O^T (64 d x 16 q) += V^T tile @ P^T  (intra-wave P reuse, no barrier needed)
#pragma unroll
    for (int df = 0; df < 4; ++df) {
      const int row = df * 16 + lo;
#pragma unroll
      for (int ks = 0; ks < 2; ++ks) {
        const hx8 vf = *(const hx8*)(Vs + row * 64 + (((ks * 4 + g) ^ (row & 7)) * 8));
        const hx8 pf = *(const hx8*)(&Ps[w][lo * 80 + ks * 32 + g * 8]);
        o[df] = __builtin_amdgcn_mfma_f32_16x16x32_f16(vf, pf, o[df], 0, 0, 0);
      }
    }
    __syncthreads();
  }

  const float inv = 1.0f / s_run;
  half_t* ob = O + (size_t)(b * NS + q) * NHID + h * DHEAD + g * 4;
#pragma unroll
  for (int df = 0; df < 4; ++df) {
    hx4 v;
#pragma unroll
    for (int j = 0; j < 4; ++j) v[j] = (half_t)(o[df][j] * inv);
    *(hx4*)(ob + df * 16) = v;
  }
}

// ---------------- row LayerNorm over 1024 ----------------
__launch_bounds__(256)
__global__ void lnorm(const float* __restrict__ y, const float* __restrict__ g,
                      const float* __restrict__ bta, float* __restrict__ out) {
  const int row = blockIdx.x;
  const int t = threadIdx.x;
  const fx4 v = ((const fx4*)(y + (size_t)row * NHID))[t];
  float s = v[0] + v[1] + v[2] + v[3];
  float sq = v[0] * v[0] + v[1] * v[1] + v[2] * v[2] + v[3] * v[3];
#pragma unroll
  for (int off = 1; off < 64; off <<= 1) {
    s += __shfl_xor(s, off);
    sq += __shfl_xor(sq, off);
  }
  __shared__ float rs[4], rsq[4];
  const int w = t >> 6;
  if ((t & 63) == 0) { rs[w] = s; rsq[w] = sq; }
  __syncthreads();
  s = rs[0] + rs[1] + rs[2] + rs[3];
  sq = rsq[0] + rsq[1] + rsq[2] + rsq[3];
  const float mu = s * (1.0f / NHID);
  const float var = sq * (1.0f / NHID) - mu * mu;
  const float rstd = rsqrtf(fmaxf(var, 0.0f) + 1e-5f);
  const fx4 gg = ((const fx4*)g)[t];
  const fx4 bb = ((const fx4*)bta)[t];
  fx4 o;
#pragma unroll
  for (int j = 0; j < 4; ++j) o[j] = (v[j] - mu) * rstd * gg[j] + bb[j];
  ((fx4*)(out + (size_t)row * NHID))[t] = o;
}

extern "C" void kernel_launch(void* const* d_in, const int* in_sizes, int n_in,
                              void* d_out, int out_size, void* d_ws, size_t ws_size,
                              hipStream_t stream) {
  const float* hidden = (const float*)d_in[0];
  const float* imp = (const float*)d_in[1];
  const float* wq = (const float*)d_in[2];  const float* bq = (const float*)d_in[3];
  const float* wk = (const float*)d_in[4];  const float* bk = (const float*)d_in[5];
  const float* wv = (const float*)d_in[6];  const float* bv = (const float*)d_in[7];
  const float* wo = (const float*)d_in[8];  const float* bo = (const float*)d_in[9];
  const float* rw1 = (const float*)d_in[10]; const float* rb1 = (const float*)d_in[11];
  const float* rw2 = (const float*)d_in[12]; const float* rb2 = (const float*)d_in[13];
  const float* aw1 = (const float*)d_in[14]; const float* ab1 = (const float*)d_in[15];
  const float* aw2 = (const float*)d_in[16]; const float* ab2 = (const float*)d_in[17];
  const float* ltemp = (const float*)d_in[18];
  const float* lng = (const float*)d_in[19]; const float* lnb = (const float*)d_in[20];

  char* ws = (char*)d_ws;
  half_t* Xb  = (half_t*)(ws);                                    // 8 MB
  half_t* Wqt = (half_t*)(ws + (size_t)(8u << 20));               // 2 MB each
  half_t* Wkt = (half_t*)(ws + (size_t)(10u << 20));
  half_t* Wvt = (half_t*)(ws + (size_t)(12u << 20));
  half_t* Wot = (half_t*)(ws + (size_t)(14u << 20));
  half_t* Qb  = (half_t*)(ws + (size_t)(16u << 20));              // 8 MB
  half_t* Kb  = (half_t*)(ws + (size_t)(24u << 20));              // 8 MB
  half_t* Vtb = (half_t*)(ws + (size_t)(32u << 20));              // 8 MB
  half_t* AO  = (half_t*)(ws + (size_t)(40u << 20));              // 8 MB
  float*  reach   = (float*)(ws + (size_t)(48u << 20));           // 256 KB
  float*  attract = (float*)(ws + (size_t)(48u << 20) + 262144);  // 256 KB
  float*  Y = (float*)(ws + (size_t)(16u << 20));  // 16 MB, aliases Qb+Kb (free after attn)

  packx<<<dim3(4096), dim3(256), 0, stream>>>(hidden, Xb);
  packw<<<dim3(32, 32, 4), dim3(32, 8), 0, stream>>>(wq, wk, wv, wo, Wqt, Wkt, Wvt, Wot);
  mlp16<<<dim3(16), dim3(256), 0, stream>>>(imp, rw1, rb1, rw2, rb2, aw1, ab1, aw2, ab2,
                                            reach, attract);
  gemm_qkv<<<dim3(32, 8, 3), dim3(256), 0, stream>>>(Xb, Wqt, Wkt, Wvt, bq, bk, bv,
                                                     Qb, Kb, Vtb);
  attn64<<<dim3(32, 32), dim3(256), 0, stream>>>(Qb, Kb, Vtb, reach, attract, ltemp, AO);
  gemm_o<<<dim3(32, 8), dim3(256), 0, stream>>>(AO, Wot, bo, hidden, Y);
  lnorm<<<dim3(4096), dim3(256), 0, stream>>>(Y, lng, lnb, (float*)d_out);
}

// Round 3
// 288.331 us; speedup vs baseline: 1.1513x; 1.1513x over previous
//
#include <hip/hip_runtime.h>
#include <math.h>

#define NB 2
#define NS 2048
#define NHID 1024
#define NHEAD 16
#define DHEAD 64

typedef _Float16 half_t;
typedef _Float16 hx4 __attribute__((ext_vector_type(4)));
typedef _Float16 hx8 __attribute__((ext_vector_type(8)));
typedef float fx4 __attribute__((ext_vector_type(4)));

#define RLN2 1.4426950408889634f
#define SCALE_Q 0.18033688011112042f  /* 0.125 / ln2 */

typedef const __attribute__((address_space(1))) void* gvp;
typedef __attribute__((address_space(3))) void* svp;

static __device__ __forceinline__ void gload16(const void* g, void* s) {
  __builtin_amdgcn_global_load_lds((gvp)g, (svp)s, 16, 0, 0);
}

static __device__ __forceinline__ float gelu_exact(float x) {
  return 0.5f * x * (1.0f + erff(x * 0.70710678118654752f));
}

// ---------------- pack hidden_states f32 -> f16 ----------------
__launch_bounds__(256)
__global__ void packx(const float* __restrict__ x, half_t* __restrict__ xb) {
  const int i = blockIdx.x * 256 + threadIdx.x;
  const fx4 v = ((const fx4*)x)[i];
  hx4 o;
#pragma unroll
  for (int j = 0; j < 4; ++j) o[j] = (half_t)v[j];
  ((hx4*)xb)[i] = o;
}

// ---------------- transpose + pack 4 weight matrices (K,N)->(N,K) f16 ----------------
__launch_bounds__(256)
__global__ void packw(const float* __restrict__ w0, const float* __restrict__ w1,
                      const float* __restrict__ w2, const float* __restrict__ w3,
                      half_t* __restrict__ o0, half_t* __restrict__ o1,
                      half_t* __restrict__ o2, half_t* __restrict__ o3) {
  __shared__ float tile[32][33];
  const int z = blockIdx.z;
  const float* w = (z == 0) ? w0 : (z == 1) ? w1 : (z == 2) ? w2 : w3;
  half_t* o = (z == 0) ? o0 : (z == 1) ? o1 : (z == 2) ? o2 : o3;
  const int n0 = blockIdx.x * 32, k0 = blockIdx.y * 32;
  const int tx = threadIdx.x, ty = threadIdx.y;  // (32,8)
#pragma unroll
  for (int i = 0; i < 4; ++i)
    tile[ty + i * 8][tx] = w[(size_t)(k0 + ty + i * 8) * NHID + n0 + tx];
  __syncthreads();
#pragma unroll
  for (int i = 0; i < 4; ++i)
    o[(size_t)(n0 + ty + i * 8) * NHID + k0 + tx] = (half_t)tile[tx][ty + i * 8];
}

// ---------------- reach/attract scalar MLPs (pre-scaled by 1/ln2) ----------------
__launch_bounds__(256)
__global__ void mlp16(const float* __restrict__ imp,
                      const float* __restrict__ rw1, const float* __restrict__ rb1,
                      const float* __restrict__ rw2, const float* __restrict__ rb2,
                      const float* __restrict__ aw1, const float* __restrict__ ab1,
                      const float* __restrict__ aw2, const float* __restrict__ ab2,
                      float* __restrict__ reach, float* __restrict__ attract) {
  const int i = blockIdx.x * 256 + threadIdx.x;  // b*NS+s
  const float v = imp[i];
  const int b = i >> 11, s = i & (NS - 1);
  float ra[16] = {}, aa[16] = {};
  for (int m = 0; m < 32; ++m) {
    const float hr = gelu_exact(v * rw1[m] + rb1[m]);
    const float ha = gelu_exact(v * aw1[m] + ab1[m]);
#pragma unroll
    for (int h = 0; h < 16; ++h) {
      ra[h] += hr * rw2[m * 16 + h];
      aa[h] += ha * aw2[m * 16 + h];
    }
  }
#pragma unroll
  for (int h = 0; h < 16; ++h) {
    reach[(size_t)(b * NHEAD + h) * NS + s] = (ra[h] + rb2[h]) * RLN2;
    attract[(size_t)(b * NHEAD + h) * NS + s] = (aa[h] + ab2[h]) * RLN2;
  }
}

// ---------------- fused QKV GEMM (all outputs (b,s,h,d), coalesced 2B stores) ----------------
__launch_bounds__(256, 2)
__global__ void gemm_qkv(const half_t* __restrict__ A,
                         const half_t* __restrict__ Wq, const half_t* __restrict__ Wk,
                         const half_t* __restrict__ Wv,
                         const float* __restrict__ bq, const float* __restrict__ bk,
                         const float* __restrict__ bv,
                         half_t* __restrict__ Qo, half_t* __restrict__ Ko,
                         half_t* __restrict__ Vo) {
  __shared__ __align__(16) half_t As[128 * 32];
  __shared__ __align__(16) half_t Bs[128 * 32];
  const int z = blockIdx.z;
  const half_t* Bt = (z == 0) ? Wq : (z == 1) ? Wk : Wv;
  const float* bias = (z == 0) ? bq : (z == 1) ? bk : bv;
  half_t* Co = (z == 0) ? Qo : (z == 1) ? Ko : Vo;
  const float oscale = (z == 0) ? SCALE_Q : 1.0f;

  const int t = threadIdx.x;
  const int l = t & 63, w = t >> 6;
  const int lo = l & 15, g = l >> 4;
  const int m0 = blockIdx.x * 128, n0 = blockIdx.y * 128;
  const int wm = (w >> 1) * 64, wn = (w & 1) * 64;
  fx4 acc[4][4] = {};

  for (int k0 = 0; k0 < NHID; k0 += 32) {
#pragma unroll
    for (int i = 0; i < 2; ++i) {
      const int c = i * 256 + t;
      const int row = c >> 2, kc = (c & 3) * 8;
      gload16(A + (size_t)(m0 + row) * NHID + k0 + kc, As + c * 8);
      gload16(Bt + (size_t)(n0 + row) * NHID + k0 + kc, Bs + c * 8);
    }
    __syncthreads();
    hx8 af[4], bfv[4];
#pragma unroll
    for (int i = 0; i < 4; ++i) {
      af[i] = *(const hx8*)(As + (wm + i * 16 + lo) * 32 + g * 8);
      bfv[i] = *(const hx8*)(Bs + (wn + i * 16 + lo) * 32 + g * 8);
    }
#pragma unroll
    for (int mi = 0; mi < 4; ++mi)
#pragma unroll
      for (int ni = 0; ni < 4; ++ni)
        acc[mi][ni] = __builtin_amdgcn_mfma_f32_16x16x32_f16(af[mi], bfv[ni], acc[mi][ni], 0, 0, 0);
    __syncthreads();
  }

#pragma unroll
  for (int mi = 0; mi < 4; ++mi) {
    const int r0 = m0 + wm + mi * 16 + g * 4;
#pragma unroll
    for (int ni = 0; ni < 4; ++ni) {
      const int col = n0 + wn + ni * 16 + lo;
      const float bs = bias[col];
#pragma unroll
      for (int j = 0; j < 4; ++j)
        Co[(size_t)(r0 + j) * NHID + col] = (half_t)((acc[mi][ni][j] + bs) * oscale);
    }
  }
}

// ---------------- V (b,s,hd) -> V^T (b,hd,s) 64x64 LDS tile transpose ----------------
__launch_bounds__(256)
__global__ void vtrans(const half_t* __restrict__ in, half_t* __restrict__ out) {
  __shared__ half_t tile[64][72];
  const int b = blockIdx.z, s0 = blockIdx.x * 64, n0 = blockIdx.y * 64;
  const int t = threadIdx.x;
  const int r = t >> 3, c = (t & 7) * 8;
  const half_t* ip = in + ((size_t)(b * NS) + s0) * NHID + n0;
#pragma unroll
  for (int i = 0; i < 2; ++i)
    *(hx8*)&tile[r + i * 32][c] = *(const hx8*)(ip + (size_t)(r + i * 32) * NHID + c);
  __syncthreads();
  half_t* op = out + ((size_t)(b * NHID) + n0) * NS + s0;
#pragma unroll
  for (int i = 0; i < 2; ++i) {
    hx8 v;
#pragma unroll
    for (int j = 0; j < 8; ++j) v[j] = tile[c + j][r + i * 32];
    *(hx8*)(op + (size_t)(r + i * 32) * NS + c) = v;
  }
}

// ---------------- output projection GEMM + bias + residual -> f32 ----------------
__launch_bounds__(256, 2)
__global__ void gemm_o(const half_t* __restrict__ A, const half_t* __restrict__ Bt,
                       const float* __restrict__ bias, const float* __restrict__ resid,
                       float* __restrict__ outf) {
  __shared__ __align__(16) half_t As[128 * 32];
  __shared__ __align__(16) half_t Bs[128 * 32];
  const int t = threadIdx.x;
  const int l = t & 63, w = t >> 6;
  const int lo = l & 15, g = l >> 4;
  const int m0 = blockIdx.x * 128, n0 = blockIdx.y * 128;
  const int wm = (w >> 1) * 64, wn = (w & 1) * 64;
  fx4 acc[4][4] = {};

  for (int k0 = 0; k0 < NHID; k0 += 32) {
#pragma unroll
    for (int i = 0; i < 2; ++i) {
      const int c = i * 256 + t;
      const int row = c >> 2, kc = (c & 3) * 8;
      gload16(A + (size_t)(m0 + row) * NHID + k0 + kc, As + c * 8);
      gload16(Bt + (size_t)(n0 + row) * NHID + k0 + kc, Bs + c * 8);
    }
    __syncthreads();
    hx8 af[4], bfv[4];
#pragma unroll
    for (int i = 0; i < 4; ++i) {
      af[i] = *(const hx8*)(As + (wm + i * 16 + lo) * 32 + g * 8);
      bfv[i] = *(const hx8*)(Bs + (wn + i * 16 + lo) * 32 + g * 8);
    }
#pragma unroll
    for (int mi = 0; mi < 4; ++mi)
#pragma unroll
      for (int ni = 0; ni < 4; ++ni)
        acc[mi][ni] = __builtin_amdgcn_mfma_f32_16x16x32_f16(af[mi], bfv[ni], acc[mi][ni], 0, 0, 0);
    __syncthreads();
  }

#pragma unroll
  for (int mi = 0; mi < 4; ++mi) {
    const int r0 = m0 + wm + mi * 16 + g * 4;
#pragma unroll
    for (int ni = 0; ni < 4; ++ni) {
      const int col = n0 + wn + ni * 16 + lo;
      const float bs = bias[col];
#pragma unroll
      for (int j = 0; j < 4; ++j) {
        const size_t idx = (size_t)(r0 + j) * NHID + col;
        outf[idx] = acc[mi][ni][j] + bs + resid[idx];
      }
    }
  }
}

// ---------------- fused flash attention, exp2 domain, P-in-registers PV ----------------
__launch_bounds__(256, 4)
__global__ void attn64(const half_t* __restrict__ Qb, const half_t* __restrict__ Kb,
                       const half_t* __restrict__ Vtb,
                       const float* __restrict__ reach, const float* __restrict__ attract,
                       const float* __restrict__ ltemp,
                       half_t* __restrict__ O) {
  __shared__ __align__(16) half_t Ks[2][64 * 64];   // swizzled (chunk ^= row&7)
  __shared__ __align__(16) half_t Vs[2][64 * 64];   // swizzled V^T tile [d][kv]
  __shared__ float apS[2][64], amS[2][64];

  const int t = threadIdx.x;
  const int l = t & 63, w = t >> 6;
  const int lo = l & 15, g = l >> 4;
  const int bh = blockIdx.y;
  const int b = bh >> 4, h = bh & 15;
  const int q0 = blockIdx.x * 64;
  const int q = q0 + w * 16 + lo;

  // everything in log2 units (reach/attract pre-scaled by 1/ln2; Q by 1/(8 ln2))
  const float ndc2 = RLN2 / ((__expf(ltemp[h]) + 1.0f) * (float)NS);
  const float rq = reach[(size_t)bh * NS + q];
  const float cqm = rq - (float)q * ndc2;
  const float cqp = rq + (float)q * ndc2;

  hx8 qf[2];
  {
    const half_t* qp = Qb + (size_t)(b * NS + q) * NHID + h * DHEAD + g * 8;
    qf[0] = *(const hx8*)(qp);
    qf[1] = *(const hx8*)(qp + 32);
  }

  fx4 o[4] = {};
  float m_run = -INFINITY, s_run = 0.0f;

  const half_t* Kbase = Kb + (size_t)b * (NS * NHID) + h * DHEAD;
  const half_t* Vbase = Vtb + (size_t)bh * (DHEAD * NS);
  const float* abase = attract + (size_t)bh * NS;

  // prologue: stage tile 0 into buffer 0
#pragma unroll
  for (int i = 0; i < 2; ++i) {
    const int c = i * 256 + t;
    const int row = c >> 3;
    const int ca = (c & 7) ^ (row & 7);
    gload16(Kbase + (size_t)row * NHID + ca * 8, &Ks[0][c * 8]);
    gload16(Vbase + (size_t)row * NS + ca * 8, &Vs[0][c * 8]);
  }
  if (t < 64) {
    const float a = abase[t];
    apS[0][t] = a + (float)t * ndc2;
    amS[0][t] = a - (float)t * ndc2;
  }
  __syncthreads();

  int buf = 0;
  for (int kv0 = 0; kv0 < NS; kv0 += 64, buf ^= 1) {
    // issue next tile's staging into the other buffer (latency hides under compute)
    if (kv0 + 64 < NS) {
      const int nb = buf ^ 1;
      const int kvn = kv0 + 64;
#pragma unroll
      for (int i = 0; i < 2; ++i) {
        const int c = i * 256 + t;
        const int row = c >> 3;
        const int ca = (c & 7) ^ (row & 7);
        gload16(Kbase + (size_t)(kvn + row) * NHID + ca * 8, &Ks[nb][c * 8]);
        gload16(Vbase + (size_t)row * NS + kvn + ca * 8, &Vs[nb][c * 8]);
      }
      if (t < 64) {
        const float a = abase[kvn + t];
        const float kvf = (float)(kvn + t);
        apS[nb][t] = a + kvf * ndc2;
        amS[nb][t] = a - kvf * ndc2;
      }
    }

    // QK^T (swapped): S^T tile, lane owns q-column lo, kv = mf*16+g*4+j
    fx4 sa[4] = {};
#pragma unroll
    for (int mf = 0; mf < 4; ++mf) {
      const int row = mf * 16 + lo;
      const half_t* kr = &Ks[buf][row * 64];
      const int rx = row & 7;
#pragma unroll
      for (int ks = 0; ks < 2; ++ks) {
        const hx8 kf = *(const hx8*)(kr + (((ks * 4 + g) ^ rx) * 8));
        sa[mf] = __builtin_amdgcn_mfma_f32_16x16x32_f16(kf, qf[ks], sa[mf], 0, 0, 0);
      }
    }

    // online softmax with defer-max (threshold 10 in log2 domain; f16 P <= 1024)
    float tmax = -1e30f;
#pragma unroll
    for (int mf = 0; mf < 4; ++mf)
#pragma unroll
      for (int j = 0; j < 4; ++j) tmax = fmaxf(tmax, sa[mf][j]);
    tmax = fmaxf(tmax, __shfl_xor(tmax, 16));
    tmax = fmaxf(tmax, __shfl_xor(tmax, 32));
    if (!__all(tmax - m_run <= 10.0f)) {
      const float m_new = fmaxf(m_run, tmax);
      const float al = __builtin_amdgcn_exp2f(m_run - m_new);
      s_run *= al;
#pragma unroll
      for (int df = 0; df < 4; ++df)
#pragma unroll
        for (int j = 0; j < 4; ++j) o[df][j] *= al;
      m_run = m_new;
    }

    float psum = 0.0f;
    hx4 pb[4];
#pragma unroll
    for (int mf = 0; mf < 4; ++mf) {
      const fx4 ap = *(const fx4*)&apS[buf][mf * 16 + g * 4];
      const fx4 am = *(const fx4*)&amS[buf][mf * 16 + g * 4];
      float pe[4];
#pragma unroll
      for (int j = 0; j < 4; ++j) {
        const float x = fminf(cqm + ap[j], cqp + am[j]);       // rq+att-|q-kv|*ndc
        const float e = __builtin_amdgcn_exp2f(sa[mf][j] - m_run);
        const float u = __builtin_amdgcn_exp2f(-x);
        const float p = e * __builtin_amdgcn_rcpf(1.0f + u);   // e * sigmoid(x)
        psum += p;
        pe[j] = p;
      }
      const auto c0 = __builtin_amdgcn_cvt_pkrtz(pe[0], pe[1]);
      const auto c1 = __builtin_amdgcn_cvt_pkrtz(pe[2], pe[3]);
      pb[mf][0] = (half_t)c0[0]; pb[mf][1] = (half_t)c0[1];
      pb[mf][2] = (half_t)c1[0]; pb[mf][3] = (half_t)c1[1];
    }
    psum += __shfl_xor(psum, 16);
    psum += __shfl_xor(psum, 32);
    s_run += psum;

    // PV via 16x16x16 MFMAs: pb IS the B-fragment (k=g*4+j, col=lo) -> no LDS round-trip
#pragma unroll
    for (int df = 0; df < 4; ++df) {
      const int r = df * 16 + lo;
      const half_t* vr = &Vs[buf][r * 64 + (g & 1) * 4];
      const int rx = r & 7;
#pragma unroll
      for (int mf = 0; mf < 4; ++mf) {
        const hx4 vf = *(const hx4*)(vr + (((2 * mf + (g >> 1)) ^ rx) * 8));
        o[df] = __builtin_amdgcn_mfma_f32_16x16x16f16(vf, pb[mf], o[df], 0, 0, 0);
      }
    }
    __syncthreads();
  }

  const float inv = 1.0f / s_run;
  half_t* ob = O + (size_t)(b * NS + q) * NHID + h * DHEAD + g * 4;
#pragma unroll
  for (int df = 0; df < 4; ++df) {
    hx4 v;
#pragma unroll
    for (int j = 0; j < 4; ++j) v[j] = (half_t)(o[df][j] * inv);
    *(hx4*)(ob + df * 16) = v;
  }
}

// ---------------- row LayerNorm over 1024 ----------------
__launch_bounds__(256)
__global__ void lnorm(const float* __restrict__ y, const float* __restrict__ g,
                      const float* __restrict__ bta, float* __restrict__ out) {
  const int row = blockIdx.x;
  const int t = threadIdx.x;
  const fx4 v = ((const fx4*)(y + (size_t)row * NHID))[t];
  float s = v[0] + v[1] + v[2] + v[3];
  float sq = v[0] * v[0] + v[1] * v[1] + v[2] * v[2] + v[3] * v[3];
#pragma unroll
  for (int off = 1; off < 64; off <<= 1) {
    s += __shfl_xor(s, off);
    sq += __shfl_xor(sq, off);
  }
  __shared__ float rs[4], rsq[4];
  const int w = t >> 6;
  if ((t & 63) == 0) { rs[w] = s; rsq[w] = sq; }
  __syncthreads();
  s = rs[0] + rs[1] + rs[2] + rs[3];
  sq = rsq[0] + rsq[1] + rsq[2] + rsq[3];
  const float mu = s * (1.0f / NHID);
  const float var = sq * (1.0f / NHID) - mu * mu;
  const float rstd = rsqrtf(fmaxf(var, 0.0f) + 1e-5f);
  const fx4 gg = ((const fx4*)g)[t];
  const fx4 bb = ((const fx4*)bta)[t];
  fx4 o;
#pragma unroll
  for (int j = 0; j < 4; ++j) o[j] = (v[j] - mu) * rstd * gg[j] + bb[j];
  ((fx4*)(out + (size_t)row * NHID))[t] = o;
}

extern "C" void kernel_launch(void* const* d_in, const int* in_sizes, int n_in,
                              void* d_out, int out_size, void* d_ws, size_t ws_size,
                              hipStream_t stream) {
  const float* hidden = (const float*)d_in[0];
  const float* imp = (const float*)d_in[1];
  const float* wq = (const float*)d_in[2];  const float* bq = (const float*)d_in[3];
  const float* wk = (const float*)d_in[4];  const float* bk = (const float*)d_in[5];
  const float* wv = (const float*)d_in[6];  const float* bv = (const float*)d_in[7];
  const float* wo = (const float*)d_in[8];  const float* bo = (const float*)d_in[9];
  const float* rw1 = (const float*)d_in[10]; const float* rb1 = (const float*)d_in[11];
  const float* rw2 = (const float*)d_in[12]; const float* rb2 = (const float*)d_in[13];
  const float* aw1 = (const float*)d_in[14]; const float* ab1 = (const float*)d_in[15];
  const float* aw2 = (const float*)d_in[16]; const float* ab2 = (const float*)d_in[17];
  const float* ltemp = (const float*)d_in[18];
  const float* lng = (const float*)d_in[19]; const float* lnb = (const float*)d_in[20];

  char* ws = (char*)d_ws;
  half_t* Xb  = (half_t*)(ws);                                    // 8 MB
  half_t* Wqt = (half_t*)(ws + (size_t)(8u << 20));               // 2 MB each
  half_t* Wkt = (half_t*)(ws + (size_t)(10u << 20));
  half_t* Wvt = (half_t*)(ws + (size_t)(12u << 20));
  half_t* Wot = (half_t*)(ws + (size_t)(14u << 20));
  half_t* Qb  = (half_t*)(ws + (size_t)(16u << 20));              // 8 MB
  half_t* Kb  = (half_t*)(ws + (size_t)(24u << 20));              // 8 MB
  half_t* Vtb = (half_t*)(ws + (size_t)(32u << 20));              // 8 MB
  half_t* Vb  = (half_t*)(ws + (size_t)(40u << 20));              // 8 MB (dead after vtrans)
  half_t* AO  = (half_t*)(ws + (size_t)(40u << 20));              // aliases Vb
  float*  reach   = (float*)(ws + (size_t)(48u << 20));           // 256 KB
  float*  attract = (float*)(ws + (size_t)(48u << 20) + 262144);  // 256 KB
  float*  Y = (float*)(ws + (size_t)(16u << 20));  // 16 MB, aliases Qb+Kb (free after attn)

  packx<<<dim3(4096), dim3(256), 0, stream>>>(hidden, Xb);
  packw<<<dim3(32, 32, 4), dim3(32, 8), 0, stream>>>(wq, wk, wv, wo, Wqt, Wkt, Wvt, Wot);
  mlp16<<<dim3(16), dim3(256), 0, stream>>>(imp, rw1, rb1, rw2, rb2, aw1, ab1, aw2, ab2,
                                            reach, attract);
  gemm_qkv<<<dim3(32, 8, 3), dim3(256), 0, stream>>>(Xb, Wqt, Wkt, Wvt, bq, bk, bv,
                                                     Qb, Kb, Vb);
  vtrans<<<dim3(32, 16, 2), dim3(256), 0, stream>>>(Vb, Vtb);
  attn64<<<dim3(32, 32), dim3(256), 0, stream>>>(Qb, Kb, Vtb, reach, attract, ltemp, AO);
  gemm_o<<<dim3(32, 8), dim3(256), 0, stream>>>(AO, Wot, bo, hidden, Y);
  lnorm<<<dim3(4096), dim3(256), 0, stream>>>(Y, lng, lnb, (float*)d_out);
}

// Round 5
// 273.334 us; speedup vs baseline: 1.2145x; 1.0549x over previous
//
#include <hip/hip_runtime.h>
#include <math.h>

#define NB 2
#define NS 2048
#define NHID 1024
#define NHEAD 16
#define DHEAD 64

typedef _Float16 half_t;
typedef _Float16 hx4 __attribute__((ext_vector_type(4)));
typedef _Float16 hx8 __attribute__((ext_vector_type(8)));
typedef float fx4 __attribute__((ext_vector_type(4)));

#define RLN2 1.4426950408889634f
#define SCALE_Q 0.18033688011112042f  /* 0.125 / ln2 */

typedef const __attribute__((address_space(1))) void* gvp;
typedef __attribute__((address_space(3))) void* svp;

static __device__ __forceinline__ void gload16(const void* g, void* s) {
  __builtin_amdgcn_global_load_lds((gvp)g, (svp)s, 16, 0, 0);
}

static __device__ __forceinline__ float gelu_exact(float x) {
  return 0.5f * x * (1.0f + erff(x * 0.70710678118654752f));
}

// ---------------- fused prep: packx (blocks 0..4095) + packw (4096..8191) ----------------
__launch_bounds__(256)
__global__ void prep(const float* __restrict__ x, half_t* __restrict__ xb,
                     const float* __restrict__ w0, const float* __restrict__ w1,
                     const float* __restrict__ w2, const float* __restrict__ w3,
                     half_t* __restrict__ o0, half_t* __restrict__ o1,
                     half_t* __restrict__ o2, half_t* __restrict__ o3) {
  __shared__ float tile[32][33];
  const int t = threadIdx.x;
  if (blockIdx.x < 4096) {
    const int i = blockIdx.x * 256 + t;
    const fx4 v = ((const fx4*)x)[i];
    hx4 o;
#pragma unroll
    for (int j = 0; j < 4; ++j) o[j] = (half_t)v[j];
    ((hx4*)xb)[i] = o;
    return;
  }
  const int bid = blockIdx.x - 4096;
  const int z = bid >> 10;
  const float* w = (z == 0) ? w0 : (z == 1) ? w1 : (z == 2) ? w2 : w3;
  half_t* o = (z == 0) ? o0 : (z == 1) ? o1 : (z == 2) ? o2 : o3;
  const int n0 = (bid & 31) * 32, k0 = ((bid >> 5) & 31) * 32;
  const int tx = t & 31, ty = t >> 5;
#pragma unroll
  for (int i = 0; i < 4; ++i)
    tile[ty + i * 8][tx] = w[(size_t)(k0 + ty + i * 8) * NHID + n0 + tx];
  __syncthreads();
#pragma unroll
  for (int i = 0; i < 4; ++i)
    o[(size_t)(n0 + ty + i * 8) * NHID + k0 + tx] = (half_t)tile[tx][ty + i * 8];
}

// ------- reach/attract MLPs -> precomputed exponentials: U1,U2 (per q) and eap,eam (per kv) -------
__launch_bounds__(256)
__global__ void mlp16(const float* __restrict__ imp,
                      const float* __restrict__ rw1, const float* __restrict__ rb1,
                      const float* __restrict__ rw2, const float* __restrict__ rb2,
                      const float* __restrict__ aw1, const float* __restrict__ ab1,
                      const float* __restrict__ aw2, const float* __restrict__ ab2,
                      const float* __restrict__ ltemp,
                      float* __restrict__ u1G, float* __restrict__ u2G,
                      float* __restrict__ eapG, float* __restrict__ eamG) {
  const int i = blockIdx.x * 256 + threadIdx.x;  // b*NS+s
  const float v = imp[i];
  const int b = i >> 11, s = i & (NS - 1);
  float ra[16] = {}, aa[16] = {};
  for (int m = 0; m < 32; ++m) {
    const float hr = gelu_exact(v * rw1[m] + rb1[m]);
    const float ha = gelu_exact(v * aw1[m] + ab1[m]);
#pragma unroll
    for (int h = 0; h < 16; ++h) {
      ra[h] += hr * rw2[m * 16 + h];
      aa[h] += ha * aw2[m * 16 + h];
    }
  }
  const float sf = (float)s;
#pragma unroll
  for (int h = 0; h < 16; ++h) {
    const float ndc2 = RLN2 / ((__expf(ltemp[h]) + 1.0f) * (float)NS);
    const float r = (ra[h] + rb2[h]) * RLN2;        // reach, log2 units
    const float a = (aa[h] + ab2[h]) * RLN2;        // attract, log2 units
    const size_t idx = (size_t)(b * NHEAD + h) * NS + s;
    u1G[idx]  = __builtin_amdgcn_exp2f(sf * ndc2 - r);
    u2G[idx]  = __builtin_amdgcn_exp2f(-sf * ndc2 - r);
    eapG[idx] = __builtin_amdgcn_exp2f(-a - sf * ndc2);
    eamG[idx] = __builtin_amdgcn_exp2f(-a + sf * ndc2);
  }
}

// ---------------- fused QKV GEMM (outputs (b,s,h,d), coalesced 2B stores) ----------------
__launch_bounds__(256, 3)
__global__ void gemm_qkv(const half_t* __restrict__ A,
                         const half_t* __restrict__ Wq, const half_t* __restrict__ Wk,
                         const half_t* __restrict__ Wv,
                         const float* __restrict__ bq, const float* __restrict__ bk,
                         const float* __restrict__ bv,
                         half_t* __restrict__ Qo, half_t* __restrict__ Ko,
                         half_t* __restrict__ Vo) {
  __shared__ __align__(16) half_t As[128 * 32];
  __shared__ __align__(16) half_t Bs[128 * 32];
  const int z = blockIdx.z;
  const half_t* Bt = (z == 0) ? Wq : (z == 1) ? Wk : Wv;
  const float* bias = (z == 0) ? bq : (z == 1) ? bk : bv;
  half_t* Co = (z == 0) ? Qo : (z == 1) ? Ko : Vo;
  const float oscale = (z == 0) ? SCALE_Q : 1.0f;

  const int t = threadIdx.x;
  const int l = t & 63, w = t >> 6;
  const int lo = l & 15, g = l >> 4;
  const int m0 = blockIdx.x * 128, n0 = blockIdx.y * 128;
  const int wm = (w >> 1) * 64, wn = (w & 1) * 64;
  fx4 acc[4][4] = {};

  for (int k0 = 0; k0 < NHID; k0 += 32) {
#pragma unroll
    for (int i = 0; i < 2; ++i) {
      const int c = i * 256 + t;
      const int row = c >> 2, kc = (c & 3) * 8;
      gload16(A + (size_t)(m0 + row) * NHID + k0 + kc, As + c * 8);
      gload16(Bt + (size_t)(n0 + row) * NHID + k0 + kc, Bs + c * 8);
    }
    __syncthreads();
    hx8 af[4], bfv[4];
#pragma unroll
    for (int i = 0; i < 4; ++i) {
      af[i] = *(const hx8*)(As + (wm + i * 16 + lo) * 32 + g * 8);
      bfv[i] = *(const hx8*)(Bs + (wn + i * 16 + lo) * 32 + g * 8);
    }
#pragma unroll
    for (int mi = 0; mi < 4; ++mi)
#pragma unroll
      for (int ni = 0; ni < 4; ++ni)
        acc[mi][ni] = __builtin_amdgcn_mfma_f32_16x16x32_f16(af[mi], bfv[ni], acc[mi][ni], 0, 0, 0);
    __syncthreads();
  }

#pragma unroll
  for (int mi = 0; mi < 4; ++mi) {
    const int r0 = m0 + wm + mi * 16 + g * 4;
#pragma unroll
    for (int ni = 0; ni < 4; ++ni) {
      const int col = n0 + wn + ni * 16 + lo;
      const float bs = bias[col];
#pragma unroll
      for (int j = 0; j < 4; ++j)
        Co[(size_t)(r0 + j) * NHID + col] = (half_t)((acc[mi][ni][j] + bs) * oscale);
    }
  }
}

// ---------------- V (b,s,hd) -> V^T (b,hd,s) 64x64 LDS tile transpose ----------------
__launch_bounds__(256)
__global__ void vtrans(const half_t* __restrict__ in, half_t* __restrict__ out) {
  __shared__ half_t tile[64][72];
  const int b = blockIdx.z, s0 = blockIdx.x * 64, n0 = blockIdx.y * 64;
  const int t = threadIdx.x;
  const int r = t >> 3, c = (t & 7) * 8;
  const half_t* ip = in + ((size_t)(b * NS) + s0) * NHID + n0;
#pragma unroll
  for (int i = 0; i < 2; ++i)
    *(hx8*)&tile[r + i * 32][c] = *(const hx8*)(ip + (size_t)(r + i * 32) * NHID + c);
  __syncthreads();
  half_t* op = out + ((size_t)(b * NHID) + n0) * NS + s0;
#pragma unroll
  for (int i = 0; i < 2; ++i) {
    hx8 v;
#pragma unroll
    for (int j = 0; j < 8; ++j) v[j] = tile[c + j][r + i * 32];
    *(hx8*)(op + (size_t)(r + i * 32) * NS + c) = v;
  }
}

// ---------------- output projection GEMM + bias + residual(f16) -> f16 Y ----------------
__launch_bounds__(256, 3)
__global__ void gemm_o(const half_t* __restrict__ A, const half_t* __restrict__ Bt,
                       const float* __restrict__ bias, const half_t* __restrict__ resid,
                       half_t* __restrict__ Yh) {
  __shared__ __align__(16) half_t As[128 * 32];
  __shared__ __align__(16) half_t Bs[128 * 32];
  const int t = threadIdx.x;
  const int l = t & 63, w = t >> 6;
  const int lo = l & 15, g = l >> 4;
  const int m0 = blockIdx.x * 128, n0 = blockIdx.y * 128;
  const int wm = (w >> 1) * 64, wn = (w & 1) * 64;
  fx4 acc[4][4] = {};

  for (int k0 = 0; k0 < NHID; k0 += 32) {
#pragma unroll
    for (int i = 0; i < 2; ++i) {
      const int c = i * 256 + t;
      const int row = c >> 2, kc = (c & 3) * 8;
      gload16(A + (size_t)(m0 + row) * NHID + k0 + kc, As + c * 8);
      gload16(Bt + (size_t)(n0 + row) * NHID + k0 + kc, Bs + c * 8);
    }
    __syncthreads();
    hx8 af[4], bfv[4];
#pragma unroll
    for (int i = 0; i < 4; ++i) {
      af[i] = *(const hx8*)(As + (wm + i * 16 + lo) * 32 + g * 8);
      bfv[i] = *(const hx8*)(Bs + (wn + i * 16 + lo) * 32 + g * 8);
    }
#pragma unroll
    for (int mi = 0; mi < 4; ++mi)
#pragma unroll
      for (int ni = 0; ni < 4; ++ni)
        acc[mi][ni] = __builtin_amdgcn_mfma_f32_16x16x32_f16(af[mi], bfv[ni], acc[mi][ni], 0, 0, 0);
    __syncthreads();
  }

#pragma unroll
  for (int mi = 0; mi < 4; ++mi) {
    const int r0 = m0 + wm + mi * 16 + g * 4;
#pragma unroll
    for (int ni = 0; ni < 4; ++ni) {
      const int col = n0 + wn + ni * 16 + lo;
      const float bs = bias[col];
#pragma unroll
      for (int j = 0; j < 4; ++j) {
        const size_t idx = (size_t)(r0 + j) * NHID + col;
        Yh[idx] = (half_t)(acc[mi][ni][j] + bs + (float)resid[idx]);
      }
    }
  }
}

// ---------------- fused flash attention: no max tracking, precomputed mask exponentials ----------------
__launch_bounds__(256, 4)
__global__ void attn64(const half_t* __restrict__ Qb, const half_t* __restrict__ Kb,
                       const half_t* __restrict__ Vtb,
                       const float* __restrict__ u1G, const float* __restrict__ u2G,
                       const float* __restrict__ eapG, const float* __restrict__ eamG,
                       half_t* __restrict__ O) {
  __shared__ __align__(16) half_t Ks[2][64 * 64];   // swizzled (chunk ^= row&7)
  __shared__ __align__(16) half_t Vs[2][64 * 64];   // swizzled V^T tile [d][kv]
  __shared__ float eapS[2][64], eamS[2][64];

  const int t = threadIdx.x;
  const int l = t & 63, w = t >> 6;
  const int lo = l & 15, g = l >> 4;
  // XCD-aware swizzle: 1024 blocks, 8 XCDs -> 4 consecutive bh per XCD (K/V L2-resident)
  const int id = blockIdx.x;
  const int swz = (id & 7) * 128 + (id >> 3);
  const int q0 = (swz & 31) * 64;
  const int bh = swz >> 5;
  const int b = bh >> 4;
  const int q = q0 + w * 16 + lo;

  const float u1 = u1G[(size_t)bh * NS + q];
  const float u2 = u2G[(size_t)bh * NS + q];

  hx8 qf[2];
  {
    const half_t* qp = Qb + (size_t)(b * NS + q) * NHID + (bh & 15) * DHEAD + g * 8;
    qf[0] = *(const hx8*)(qp);
    qf[1] = *(const hx8*)(qp + 32);
  }

  fx4 o[4] = {};
  float s_run = 0.0f;
  const auto one2 = __builtin_amdgcn_cvt_pkrtz(1.0f, 1.0f);

  const half_t* Kbase = Kb + (size_t)b * (NS * NHID) + (bh & 15) * DHEAD;
  const half_t* Vbase = Vtb + (size_t)bh * (DHEAD * NS);
  const float* eapb = eapG + (size_t)bh * NS;
  const float* eamb = eamG + (size_t)bh * NS;

  // prologue: stage tile 0 into buffer 0
#pragma unroll
  for (int i = 0; i < 2; ++i) {
    const int c = i * 256 + t;
    const int row = c >> 3;
    const int ca = (c & 7) ^ (row & 7);
    gload16(Kbase + (size_t)row * NHID + ca * 8, &Ks[0][c * 8]);
    gload16(Vbase + (size_t)row * NS + ca * 8, &Vs[0][c * 8]);
  }
  if (t < 64) eapS[0][t] = eapb[t];
  else if (t < 128) eamS[0][t - 64] = eamb[t - 64];
  __syncthreads();

  int buf = 0;
  for (int kv0 = 0; kv0 < NS; kv0 += 64, buf ^= 1) {
    if (kv0 + 64 < NS) {
      const int nb = buf ^ 1;
      const int kvn = kv0 + 64;
#pragma unroll
      for (int i = 0; i < 2; ++i) {
        const int c = i * 256 + t;
        const int row = c >> 3;
        const int ca = (c & 7) ^ (row & 7);
        gload16(Kbase + (size_t)(kvn + row) * NHID + ca * 8, &Ks[nb][c * 8]);
        gload16(Vbase + (size_t)row * NS + kvn + ca * 8, &Vs[nb][c * 8]);
      }
      if (t < 64) eapS[nb][t] = eapb[kvn + t];
      else if (t < 128) eamS[nb][t - 64] = eamb[kvn + t - 64];
    }

    // QK^T (swapped): lane owns q-column lo, kv = mf*16 + g*4 + j
    fx4 sa[4] = {};
#pragma unroll
    for (int mf = 0; mf < 4; ++mf) {
      const int row = mf * 16 + lo;
      const half_t* kr = &Ks[buf][row * 64];
      const int rx = row & 7;
#pragma unroll
      for (int ks = 0; ks < 2; ++ks) {
        const hx8 kf = *(const hx8*)(kr + (((ks * 4 + g) ^ rx) * 8));
        sa[mf] = __builtin_amdgcn_mfma_f32_16x16x32_f16(kf, qf[ks], sa[mf], 0, 0, 0);
      }
    }

    // p = 2^sa * sigmoid(x);  u = 2^-x = max(u1*eap[kv], u2*eam[kv])  (all precomputed exps)
    float psum = s_run;
    hx4 pb[4];
#pragma unroll
    for (int mf = 0; mf < 4; ++mf) {
      const fx4 ea = *(const fx4*)&eapS[buf][mf * 16 + g * 4];
      const fx4 em = *(const fx4*)&eamS[buf][mf * 16 + g * 4];
      float pe[4];
#pragma unroll
      for (int j = 0; j < 4; ++j) {
        const float u = fmaxf(u1 * ea[j], u2 * em[j]);
        const float e = __builtin_amdgcn_exp2f(sa[mf][j]);
        pe[j] = e * __builtin_amdgcn_rcpf(1.0f + u);
      }
      const auto c0 = __builtin_amdgcn_cvt_pkrtz(pe[0], pe[1]);
      const auto c1 = __builtin_amdgcn_cvt_pkrtz(pe[2], pe[3]);
      psum = __builtin_amdgcn_fdot2(c0, one2, psum, false);
      psum = __builtin_amdgcn_fdot2(c1, one2, psum, false);
      pb[mf][0] = (half_t)c0[0]; pb[mf][1] = (half_t)c0[1];
      pb[mf][2] = (half_t)c1[0]; pb[mf][3] = (half_t)c1[1];
    }
    s_run = psum;

    // PV via 16x16x16 MFMAs: pb IS the B-fragment (k=g*4+j, col=lo)
#pragma unroll
    for (int df = 0; df < 4; ++df) {
      const int r = df * 16 + lo;
      const half_t* vr = &Vs[buf][r * 64 + (g & 1) * 4];
      const int rx = r & 7;
#pragma unroll
      for (int mf = 0; mf < 4; ++mf) {
        const hx4 vf = *(const hx4*)(vr + (((2 * mf + (g >> 1)) ^ rx) * 8));
        o[df] = __builtin_amdgcn_mfma_f32_16x16x16f16(vf, pb[mf], o[df], 0, 0, 0);
      }
    }
    __syncthreads();
  }

  s_run += __shfl_xor(s_run, 16);
  s_run += __shfl_xor(s_run, 32);
  const float inv = 1.0f / s_run;
  half_t* ob = O + (size_t)(b * NS + q) * NHID + (bh & 15) * DHEAD + g * 4;
#pragma unroll
  for (int df = 0; df < 4; ++df) {
    hx4 v;
#pragma unroll
    for (int j = 0; j < 4; ++j) v[j] = (half_t)(o[df][j] * inv);
    *(hx4*)(ob + df * 16) = v;
  }
}

// ---------------- row LayerNorm over 1024 (f16 in, f32 out) ----------------
__launch_bounds__(256)
__global__ void lnorm(const half_t* __restrict__ y, const float* __restrict__ g,
                      const float* __restrict__ bta, float* __restrict__ out) {
  const int row = blockIdx.x;
  const int t = threadIdx.x;
  const hx4 vh = ((const hx4*)(y + (size_t)row * NHID))[t];
  fx4 v;
#pragma unroll
  for (int j = 0; j < 4; ++j) v[j] = (float)vh[j];
  float s = v[0] + v[1] + v[2] + v[3];
  float sq = v[0] * v[0] + v[1] * v[1] + v[2] * v[2] + v[3] * v[3];
#pragma unroll
  for (int off = 1; off < 64; off <<= 1) {
    s += __shfl_xor(s, off);
    sq += __shfl_xor(sq, off);
  }
  __shared__ float rs[4], rsq[4];
  const int w = t >> 6;
  if ((t & 63) == 0) { rs[w] = s; rsq[w] = sq; }
  __syncthreads();
  s = rs[0] + rs[1] + rs[2] + rs[3];
  sq = rsq[0] + rsq[1] + rsq[2] + rsq[3];
  const float mu = s * (1.0f / NHID);
  const float var = sq * (1.0f / NHID) - mu * mu;
  const float rstd = rsqrtf(fmaxf(var, 0.0f) + 1e-5f);
  const fx4 gg = ((const fx4*)g)[t];
  const fx4 bb = ((const fx4*)bta)[t];
  fx4 o;
#pragma unroll
  for (int j = 0; j < 4; ++j) o[j] = (v[j] - mu) * rstd * gg[j] + bb[j];
  ((fx4*)(out + (size_t)row * NHID))[t] = o;
}

extern "C" void kernel_launch(void* const* d_in, const int* in_sizes, int n_in,
                              void* d_out, int out_size, void* d_ws, size_t ws_size,
                              hipStream_t stream) {
  const float* hidden = (const float*)d_in[0];
  const float* imp = (const float*)d_in[1];
  const float* wq = (const float*)d_in[2];  const float* bq = (const float*)d_in[3];
  const float* wk = (const float*)d_in[4];  const float* bk = (const float*)d_in[5];
  const float* wv = (const float*)d_in[6];  const float* bv = (const float*)d_in[7];
  const float* wo = (const float*)d_in[8];  const float* bo = (const float*)d_in[9];
  const float* rw1 = (const float*)d_in[10]; const float* rb1 = (const float*)d_in[11];
  const float* rw2 = (const float*)d_in[12]; const float* rb2 = (const float*)d_in[13];
  const float* aw1 = (const float*)d_in[14]; const float* ab1 = (const float*)d_in[15];
  const float* aw2 = (const float*)d_in[16]; const float* ab2 = (const float*)d_in[17];
  const float* ltemp = (const float*)d_in[18];
  const float* lng = (const float*)d_in[19]; const float* lnb = (const float*)d_in[20];

  char* ws = (char*)d_ws;
  half_t* Xb  = (half_t*)(ws);                                    // 8 MB
  half_t* Wqt = (half_t*)(ws + (size_t)(8u << 20));               // 2 MB each
  half_t* Wkt = (half_t*)(ws + (size_t)(10u << 20));
  half_t* Wvt = (half_t*)(ws + (size_t)(12u << 20));
  half_t* Wot = (half_t*)(ws + (size_t)(14u << 20));
  half_t* Qb  = (half_t*)(ws + (size_t)(16u << 20));              // 8 MB
  half_t* Kb  = (half_t*)(ws + (size_t)(24u << 20));              // 8 MB
  half_t* Vtb = (half_t*)(ws + (size_t)(32u << 20));              // 8 MB
  half_t* Vb  = (half_t*)(ws + (size_t)(40u << 20));              // 8 MB (dead after vtrans)
  half_t* AO  = (half_t*)(ws + (size_t)(40u << 20));              // aliases Vb
  float*  u1G  = (float*)(ws + (size_t)(48u << 20));              // 512 KB each
  float*  u2G  = (float*)(ws + (size_t)(48u << 20) + 524288);
  float*  eapG = (float*)(ws + (size_t)(48u << 20) + 1048576);
  float*  eamG = (float*)(ws + (size_t)(48u << 20) + 1572864);
  half_t* Y = (half_t*)(ws + (size_t)(16u << 20));  // 8 MB, aliases Qb (free after attn)

  prep<<<dim3(8192), dim3(256), 0, stream>>>(hidden, Xb, wq, wk, wv, wo,
                                             Wqt, Wkt, Wvt, Wot);
  mlp16<<<dim3(16), dim3(256), 0, stream>>>(imp, rw1, rb1, rw2, rb2, aw1, ab1, aw2, ab2,
                                            ltemp, u1G, u2G, eapG, eamG);
  gemm_qkv<<<dim3(32, 8, 3), dim3(256), 0, stream>>>(Xb, Wqt, Wkt, Wvt, bq, bk, bv,
                                                     Qb, Kb, Vb);
  vtrans<<<dim3(32, 16, 2), dim3(256), 0, stream>>>(Vb, Vtb);
  attn64<<<dim3(1024), dim3(256), 0, stream>>>(Qb, Kb, Vtb, u1G, u2G, eapG, eamG, AO);
  gemm_o<<<dim3(32, 8), dim3(256), 0, stream>>>(AO, Wot, bo, Xb, Y);
  lnorm<<<dim3(4096), dim3(256), 0, stream>>>(Y, lng, lnb, (float*)d_out);
}